// Round 1
// baseline (389.833 us; speedup 1.0000x reference)
//
#include <hip/hip_runtime.h>

#define C_CH 256
#define T_SZ 16
#define H_SZ 64
#define W_SZ 64
#define TGN 5
#define HGN 8
#define WGN 8
#define TDN 4
#define AHN 7
#define AWN 7
#define CH 8   // channels per LDS chunk

__global__ __launch_bounds__(256) void roialign3d_kernel(
    const float* __restrict__ features,
    const float* __restrict__ rois,
    float* __restrict__ out)
{
    const int r   = blockIdx.x;
    const int tid = threadIdx.x;

    __shared__ int   sT0[TGN]; __shared__ float sTW0[TGN], sTW1[TGN];
    __shared__ int   sH0[HGN]; __shared__ float sHW0[HGN], sHW1[HGN];
    __shared__ int   sW0[WGN]; __shared__ float sWW0[WGN], sWW1[WGN];
    __shared__ int   sB;
    __shared__ float samp[CH][TGN*HGN*WGN];   // 8 * 320 * 4B = 10.2 KB

    const float* roi = rois + (size_t)r * 7;

    if (tid == 0) sB = (int)roi[0];
    if (tid < TGN) {
        // temporal axis: start=rois[3]*1.0, end=rois[6]*1.0, n=5, size=16
        float start = roi[3];
        float end   = roi[6];
        float bin   = fmaxf(end - start, 0.0f) / (float)(TGN - 1);
        float c     = start + bin * (float)tid;
        float lo    = fminf(fmaxf(floorf(c), 0.0f), (float)(T_SZ - 2));
        float f     = c - lo;
        float v     = (c >= 0.0f && c < (float)T_SZ) ? 1.0f : 0.0f;
        sT0[tid]  = (int)lo;
        sTW0[tid] = v * (1.0f - f);
        sTW1[tid] = v * f;
    } else if (tid >= 8 && tid < 8 + HGN) {
        // h axis: rois[2]*0.0625 .. rois[5]*0.0625, n=8, size=64
        int g = tid - 8;
        float start = roi[2] * 0.0625f;
        float end   = roi[5] * 0.0625f;
        float bin   = fmaxf(end - start, 0.0f) / (float)(HGN - 1);
        float c     = start + bin * (float)g;
        float lo    = fminf(fmaxf(floorf(c), 0.0f), (float)(H_SZ - 2));
        float f     = c - lo;
        float v     = (c >= 0.0f && c < (float)H_SZ) ? 1.0f : 0.0f;
        sH0[g]  = (int)lo;
        sHW0[g] = v * (1.0f - f);
        sHW1[g] = v * f;
    } else if (tid >= 16 && tid < 16 + WGN) {
        // w axis: rois[1]*0.0625 .. rois[4]*0.0625, n=8, size=64
        int g = tid - 16;
        float start = roi[1] * 0.0625f;
        float end   = roi[4] * 0.0625f;
        float bin   = fmaxf(end - start, 0.0f) / (float)(WGN - 1);
        float c     = start + bin * (float)g;
        float lo    = fminf(fmaxf(floorf(c), 0.0f), (float)(W_SZ - 2));
        float f     = c - lo;
        float v     = (c >= 0.0f && c < (float)W_SZ) ? 1.0f : 0.0f;
        sW0[g]  = (int)lo;
        sWW0[g] = v * (1.0f - f);
        sWW1[g] = v * f;
    }
    __syncthreads();

    const size_t cstride = (size_t)T_SZ * H_SZ * W_SZ;   // 65536
    const float* fb_batch = features + (size_t)sB * C_CH * cstride;

    const int NSAMP = TGN * HGN * WGN;   // 320
    const int NOUT  = TDN * AHN * AWN;   // 196

    for (int c0 = 0; c0 < C_CH; c0 += CH) {
        // ---- phase 1: trilinear samples into LDS ----
        for (int t = tid; t < CH * NSAMP; t += 256) {
            int cc  = t / NSAMP;
            int rem = t - cc * NSAMP;
            int tg  = rem >> 6;         // /64
            int hg  = (rem >> 3) & 7;
            int wg  = rem & 7;

            int   t0  = sT0[tg]; float tw0 = sTW0[tg], tw1 = sTW1[tg];
            int   h0  = sH0[hg]; float hw0 = sHW0[hg], hw1 = sHW1[hg];
            int   w0  = sW0[wg]; float ww0 = sWW0[wg], ww1 = sWW1[wg];

            const float* p0 = fb_batch + (size_t)(c0 + cc) * cstride
                            + (size_t)t0 * (H_SZ * W_SZ) + h0 * W_SZ + w0;

            float f000 = p0[0];
            float f001 = p0[1];
            float f010 = p0[W_SZ];
            float f011 = p0[W_SZ + 1];
            float f100 = p0[H_SZ * W_SZ];
            float f101 = p0[H_SZ * W_SZ + 1];
            float f110 = p0[H_SZ * W_SZ + W_SZ];
            float f111 = p0[H_SZ * W_SZ + W_SZ + 1];

            float v0 = hw0 * (ww0 * f000 + ww1 * f001)
                     + hw1 * (ww0 * f010 + ww1 * f011);
            float v1 = hw0 * (ww0 * f100 + ww1 * f101)
                     + hw1 * (ww0 * f110 + ww1 * f111);
            samp[cc][rem] = tw0 * v0 + tw1 * v1;
        }
        __syncthreads();

        // ---- phase 2: 2x2x2 pair-pool + coalesced store ----
        for (int t = tid; t < CH * NOUT; t += 256) {
            int cc = t / NOUT;
            int s  = t - cc * NOUT;
            int td = s / 49;
            int r2 = s - td * 49;
            int ah = r2 / 7;
            int aw = r2 - ah * 7;

            const float* sp = &samp[cc][(td << 6) + (ah << 3) + aw];
            float acc = sp[0] + sp[1] + sp[8] + sp[9]
                      + sp[64] + sp[65] + sp[72] + sp[73];
            out[((size_t)r * C_CH + (c0 + cc)) * NOUT + s] = 0.125f * acc;
        }
        __syncthreads();
    }
}

extern "C" void kernel_launch(void* const* d_in, const int* in_sizes, int n_in,
                              void* d_out, int out_size, void* d_ws, size_t ws_size,
                              hipStream_t stream) {
    const float* features = (const float*)d_in[0];
    const float* rois     = (const float*)d_in[1];
    float* out            = (float*)d_out;

    int R = in_sizes[1] / 7;   // 1024
    hipLaunchKernelGGL(roialign3d_kernel, dim3(R), dim3(256), 0, stream,
                       features, rois, out);
}

// Round 2
// 207.803 us; speedup vs baseline: 1.8760x; 1.8760x over previous
//
#include <hip/hip_runtime.h>

#define C_CH 256
#define T_SZ 16
#define H_SZ 64
#define W_SZ 64
#define TGN 5
#define HGN 8
#define WGN 8
#define TDN 4
#define AHN 7
#define AWN 7
#define CH 8                      // channels per block
#define NSAMP (TGN*HGN*WGN)       // 320
#define NOUT  (TDN*AHN*AWN)       // 196

__global__ __launch_bounds__(256, 8) void roialign3d_kernel(
    const float* __restrict__ features,
    const float* __restrict__ rois,
    float* __restrict__ out)
{
    const int r   = blockIdx.x;
    const int c0  = blockIdx.y * CH;
    const int tid = threadIdx.x;

    __shared__ int   sT0[TGN]; __shared__ float sTW0[TGN], sTW1[TGN];
    __shared__ int   sH0[HGN]; __shared__ float sHW0[HGN], sHW1[HGN];
    __shared__ int   sW0[WGN]; __shared__ float sWW0[WGN], sWW1[WGN];
    __shared__ int   sB;
    __shared__ float samp[CH][NSAMP];   // 8 * 320 * 4B = 10.24 KB

    const float* roi = rois + (size_t)r * 7;

    if (tid == 0) sB = (int)roi[0];
    if (tid < TGN) {
        // temporal axis: start=rois[3]*1.0, end=rois[6]*1.0, n=5, size=16
        float start = roi[3];
        float end   = roi[6];
        float bin   = fmaxf(end - start, 0.0f) / (float)(TGN - 1);
        float c     = start + bin * (float)tid;
        float lo    = fminf(fmaxf(floorf(c), 0.0f), (float)(T_SZ - 2));
        float f     = c - lo;
        float v     = (c >= 0.0f && c < (float)T_SZ) ? 1.0f : 0.0f;
        sT0[tid]  = (int)lo;
        sTW0[tid] = v * (1.0f - f);
        sTW1[tid] = v * f;
    } else if (tid >= 8 && tid < 8 + HGN) {
        int g = tid - 8;
        float start = roi[2] * 0.0625f;
        float end   = roi[5] * 0.0625f;
        float bin   = fmaxf(end - start, 0.0f) / (float)(HGN - 1);
        float c     = start + bin * (float)g;
        float lo    = fminf(fmaxf(floorf(c), 0.0f), (float)(H_SZ - 2));
        float f     = c - lo;
        float v     = (c >= 0.0f && c < (float)H_SZ) ? 1.0f : 0.0f;
        sH0[g]  = (int)lo;
        sHW0[g] = v * (1.0f - f);
        sHW1[g] = v * f;
    } else if (tid >= 16 && tid < 16 + WGN) {
        int g = tid - 16;
        float start = roi[1] * 0.0625f;
        float end   = roi[4] * 0.0625f;
        float bin   = fmaxf(end - start, 0.0f) / (float)(WGN - 1);
        float c     = start + bin * (float)g;
        float lo    = fminf(fmaxf(floorf(c), 0.0f), (float)(W_SZ - 2));
        float f     = c - lo;
        float v     = (c >= 0.0f && c < (float)W_SZ) ? 1.0f : 0.0f;
        sW0[g]  = (int)lo;
        sWW0[g] = v * (1.0f - f);
        sWW1[g] = v * f;
    }
    __syncthreads();

    const size_t cstride = (size_t)T_SZ * H_SZ * W_SZ;   // 65536
    const float* fb = features + ((size_t)sB * C_CH + c0) * cstride;

    // ---- phase 1: trilinear samples into LDS (exactly 10 iters/thread) ----
    #pragma unroll
    for (int it = 0; it < (CH * NSAMP) / 256; ++it) {
        int t   = tid + it * 256;
        int cc  = t / NSAMP;
        int rem = t - cc * NSAMP;
        int tg  = rem >> 6;         // /64
        int hg  = (rem >> 3) & 7;
        int wg  = rem & 7;

        int   t0  = sT0[tg]; float tw0 = sTW0[tg], tw1 = sTW1[tg];
        int   h0  = sH0[hg]; float hw0 = sHW0[hg], hw1 = sHW1[hg];
        int   w0  = sW0[wg]; float ww0 = sWW0[wg], ww1 = sWW1[wg];

        const float* p0 = fb + (size_t)cc * cstride
                        + (size_t)t0 * (H_SZ * W_SZ) + h0 * W_SZ + w0;

        float f000 = p0[0];
        float f001 = p0[1];
        float f010 = p0[W_SZ];
        float f011 = p0[W_SZ + 1];
        float f100 = p0[H_SZ * W_SZ];
        float f101 = p0[H_SZ * W_SZ + 1];
        float f110 = p0[H_SZ * W_SZ + W_SZ];
        float f111 = p0[H_SZ * W_SZ + W_SZ + 1];

        float v0 = hw0 * (ww0 * f000 + ww1 * f001)
                 + hw1 * (ww0 * f010 + ww1 * f011);
        float v1 = hw0 * (ww0 * f100 + ww1 * f101)
                 + hw1 * (ww0 * f110 + ww1 * f111);
        samp[cc][rem] = tw0 * v0 + tw1 * v1;
    }
    __syncthreads();

    // ---- phase 2: 2x2x2 pair-pool + coalesced nontemporal store ----
    for (int t = tid; t < CH * NOUT; t += 256) {
        int cc = t / NOUT;
        int s  = t - cc * NOUT;
        int td = s / 49;
        int r2 = s - td * 49;
        int ah = r2 / 7;
        int aw = r2 - ah * 7;

        const float* sp = &samp[cc][(td << 6) + (ah << 3) + aw];
        float acc = sp[0] + sp[1] + sp[8] + sp[9]
                  + sp[64] + sp[65] + sp[72] + sp[73];
        __builtin_nontemporal_store(0.125f * acc,
            &out[((size_t)r * C_CH + (c0 + cc)) * NOUT + s]);
    }
}

extern "C" void kernel_launch(void* const* d_in, const int* in_sizes, int n_in,
                              void* d_out, int out_size, void* d_ws, size_t ws_size,
                              hipStream_t stream) {
    const float* features = (const float*)d_in[0];
    const float* rois     = (const float*)d_in[1];
    float* out            = (float*)d_out;

    int R = in_sizes[1] / 7;   // 1024
    hipLaunchKernelGGL(roialign3d_kernel, dim3(R, C_CH / CH), dim3(256), 0, stream,
                       features, rois, out);
}

// Round 3
// 167.583 us; speedup vs baseline: 2.3262x; 1.2400x over previous
//
#include <hip/hip_runtime.h>

#define C_CH 256
#define T_SZ 16
#define H_SZ 64
#define W_SZ 64
#define TGN 5
#define HGN 8
#define WGN 8
#define CH 8
#define NSAMP (TGN*HGN*WGN)       // 320
#define NOUT  (4*7*7)             // 196

__global__ __launch_bounds__(256, 8) void roialign3d_kernel(
    const float* __restrict__ features,
    const float* __restrict__ rois,
    float* __restrict__ out)
{
    // XCD-phased decode: 4 super-rounds x (1024 rois x 8 chunk-lanes).
    // With round-robin block->XCD dispatch, XCD x sees only chunk (sr*8+x):
    // a 2ch-batch slab of 2x2MB that exactly fits its private L2 for all rois.
    const int bid   = blockIdx.x;
    const int sr    = bid >> 13;          // super-round (0..3)
    const int rem   = bid & 8191;
    const int r     = rem >> 3;           // roi
    const int chunk = (sr << 3) | (rem & 7);
    const int c0    = chunk * CH;

    const int tid  = threadIdx.x;
    const int lane = tid & 63;
    const int wid  = tid >> 6;
    const int hg   = lane >> 3;           // lane-invariant (h,w) grid point
    const int wg   = lane & 7;

    __shared__ float samp[CH][NSAMP];     // 10.24 KB

    const float* roi = rois + r * 7;
    const float rb  = roi[0];
    const float rx1 = roi[1], ry1 = roi[2], rt1 = roi[3];
    const float rx2 = roi[4], ry2 = roi[5], rt2 = roi[6];

    // ---- per-lane h axis ----
    const float hs = ry1 * 0.0625f, he = ry2 * 0.0625f;
    const float hbin = fmaxf(he - hs, 0.0f) * (1.0f / 7.0f);
    const float hc  = hs + hbin * (float)hg;
    const float hlo = fminf(fmaxf(floorf(hc), 0.0f), 62.0f);
    const float hf  = hc - hlo;
    const float hv  = (hc >= 0.0f && hc < 64.0f) ? 1.0f : 0.0f;
    const int   h0  = (int)hlo;
    const float hw0 = hv * (1.0f - hf), hw1 = hv * hf;

    // ---- per-lane w axis ----
    const float wss = rx1 * 0.0625f, wee = rx2 * 0.0625f;
    const float wbin = fmaxf(wee - wss, 0.0f) * (1.0f / 7.0f);
    const float wcc = wss + wbin * (float)wg;
    const float wlo = fminf(fmaxf(floorf(wcc), 0.0f), 62.0f);
    const float wf  = wcc - wlo;
    const float wv  = (wcc >= 0.0f && wcc < 64.0f) ? 1.0f : 0.0f;
    const int   w0  = (int)wlo;
    const float ww0 = wv * (1.0f - wf), ww1 = wv * wf;

    // combined bilinear weights (loop-invariant registers)
    const float w00 = hw0 * ww0, w01 = hw0 * ww1;
    const float w10 = hw1 * ww0, w11 = hw1 * ww1;
    const int hw_off = h0 * W_SZ + w0;

    // ---- t axis: 5 entries in registers (uniform across lanes, cheap) ----
    const float tbin = fmaxf(rt2 - rt1, 0.0f) * 0.25f;
    int t0a[TGN]; float tw0a[TGN], tw1a[TGN];
    #pragma unroll
    for (int i = 0; i < TGN; ++i) {
        float c  = rt1 + tbin * (float)i;
        float lo = fminf(fmaxf(floorf(c), 0.0f), 14.0f);
        float f  = c - lo;
        float v  = (c >= 0.0f && c < 16.0f) ? 1.0f : 0.0f;
        t0a[i]  = (int)lo;
        tw0a[i] = v * (1.0f - f);
        tw1a[i] = v * f;
    }

    const int cstride = T_SZ * H_SZ * W_SZ;   // 65536
    const float* fb = features
        + ((size_t)(int)rb * C_CH + (size_t)(c0 + wid * 2)) * cstride + hw_off;

    // ---- phase 1: wave = fixed (h,w); loop 2 channels x 5 t-levels ----
    #pragma unroll
    for (int ccl = 0; ccl < 2; ++ccl) {
        const int cc = wid * 2 + ccl;
        const float* fc = fb + ccl * cstride;
        #pragma unroll
        for (int tg = 0; tg < TGN; ++tg) {
            const float* p0 = fc + t0a[tg] * (H_SZ * W_SZ);
            const float* p1 = p0 + H_SZ * W_SZ;
            float a00 = p0[0], a01 = p0[1], a10 = p0[W_SZ], a11 = p0[W_SZ + 1];
            float b00 = p1[0], b01 = p1[1], b10 = p1[W_SZ], b11 = p1[W_SZ + 1];
            float v0 = a00 * w00 + a01 * w01 + a10 * w10 + a11 * w11;
            float v1 = b00 * w00 + b01 * w01 + b10 * w10 + b11 * w11;
            samp[cc][tg * 64 + lane] = tw0a[tg] * v0 + tw1a[tg] * v1;
        }
    }
    __syncthreads();

    // ---- phase 2: 2x2x2 pair-pool + coalesced nontemporal store ----
    for (int t = tid; t < CH * NOUT; t += 256) {
        int cc = t / NOUT;
        int s  = t - cc * NOUT;
        int td = s / 49;
        int r2 = s - td * 49;
        int ah = r2 / 7;
        int aw = r2 - ah * 7;

        const float* sp = &samp[cc][(td << 6) + (ah << 3) + aw];
        float acc = sp[0] + sp[1] + sp[8] + sp[9]
                  + sp[64] + sp[65] + sp[72] + sp[73];
        __builtin_nontemporal_store(0.125f * acc,
            &out[((size_t)r * C_CH + (c0 + cc)) * NOUT + s]);
    }
}

extern "C" void kernel_launch(void* const* d_in, const int* in_sizes, int n_in,
                              void* d_out, int out_size, void* d_ws, size_t ws_size,
                              hipStream_t stream) {
    const float* features = (const float*)d_in[0];
    const float* rois     = (const float*)d_in[1];
    float* out            = (float*)d_out;

    int R = in_sizes[1] / 7;   // 1024
    int nblocks = R * (C_CH / CH);
    hipLaunchKernelGGL(roialign3d_kernel, dim3(nblocks), dim3(256), 0, stream,
                       features, rois, out);
}

// Round 4
// 131.919 us; speedup vs baseline: 2.9551x; 1.2704x over previous
//
#include <hip/hip_runtime.h>

#define C_CH 256
#define T_SZ 16
#define H_SZ 64
#define W_SZ 64
#define TGN 5
#define CH 8
#define HWs (H_SZ * W_SZ)          // 4096
#define CSTR (T_SZ * HWs)          // 65536
#define NOUT 196

__device__ __forceinline__ float2 ld2(const float* p) {
    float2 v;
    __builtin_memcpy(&v, p, sizeof(float2));
    return v;
}

__global__ __launch_bounds__(256, 8) void roialign3d_kernel(
    const float* __restrict__ features,
    const float* __restrict__ rois,
    float* __restrict__ out)
{
    // XCD-phased decode: 4 super-rounds x (1024 rois x 8 chunk-lanes).
    // Each XCD sees one 8-channel x 2-batch slab (4 MB = its L2) per round.
    const int bid   = blockIdx.x;
    const int sr    = bid >> 13;
    const int rem   = bid & 8191;
    const int r     = rem >> 3;
    const int chunk = (sr << 3) | (rem & 7);
    const int c0    = chunk * CH;

    const int tid  = threadIdx.x;
    const int lane = tid & 63;
    const int wid  = tid >> 6;
    const int hg   = lane >> 3;    // fixed (h,w) grid point per lane
    const int wg   = lane & 7;

    const float* roi = rois + r * 7;
    const int   b   = (int)roi[0];
    const float rx1 = roi[1], ry1 = roi[2], rt1 = roi[3];
    const float rx2 = roi[4], ry2 = roi[5], rt2 = roi[6];

    // ---- per-lane h axis ----
    const float hs = ry1 * 0.0625f, he = ry2 * 0.0625f;
    const float hbin = fmaxf(he - hs, 0.0f) * (1.0f / 7.0f);
    const float hc  = hs + hbin * (float)hg;
    const float hlo = fminf(fmaxf(floorf(hc), 0.0f), 62.0f);
    const float hf  = hc - hlo;
    const float hv  = (hc >= 0.0f && hc < 64.0f) ? 1.0f : 0.0f;
    const int   h0  = (int)hlo;
    const float hw0 = hv * (1.0f - hf), hw1 = hv * hf;

    // ---- per-lane w axis ----
    const float wss = rx1 * 0.0625f, wee = rx2 * 0.0625f;
    const float wbin = fmaxf(wee - wss, 0.0f) * (1.0f / 7.0f);
    const float wc  = wss + wbin * (float)wg;
    const float wlo = fminf(fmaxf(floorf(wc), 0.0f), 62.0f);
    const float wf  = wc - wlo;
    const float wv  = (wc >= 0.0f && wc < 64.0f) ? 1.0f : 0.0f;
    const int   w0  = (int)wlo;
    const float ww0 = wv * (1.0f - wf), ww1 = wv * wf;

    // combined bilinear weights (loop-invariant)
    const float w00 = hw0 * ww0, w01 = hw0 * ww1;
    const float w10 = hw1 * ww0, w11 = hw1 * ww1;
    const int hw_off = h0 * W_SZ + w0;

    // ---- t table (uniform across the block) ----
    const float tbin = fmaxf(rt2 - rt1, 0.0f) * 0.25f;
    int t0a[TGN]; float tw0a[TGN], tw1a[TGN];
    #pragma unroll
    for (int i = 0; i < TGN; ++i) {
        float c  = rt1 + tbin * (float)i;
        float lo = fminf(fmaxf(floorf(c), 0.0f), 14.0f);
        float f  = c - lo;
        float v  = (c >= 0.0f && c < 16.0f) ? 1.0f : 0.0f;
        t0a[i]  = (int)lo;
        tw0a[i] = v * (1.0f - f);
        tw1a[i] = v * f;
    }

    const float* fb = features
        + ((size_t)b * C_CH + (size_t)(c0 + wid * 2)) * CSTR + hw_off;

    const bool active = (hg < 7) && (wg < 7);
    const int  s_hw   = hg * 7 + wg;

    #pragma unroll
    for (int ccl = 0; ccl < 2; ++ccl) {
        const int cc = wid * 2 + ccl;
        const float* fc = fb + ccl * CSTR;

        // ---- bilinear samples across 5 t-levels, slice-cached ----
        float s[TGN];
        int   ta_p = -1000;
        float bil_a = 0.0f, bil_b = 0.0f;
        #pragma unroll
        for (int tg = 0; tg < TGN; ++tg) {
            const int ta = __builtin_amdgcn_readfirstlane(t0a[tg]);
            float v0, v1;
            if (ta == ta_p) {            // both slices cached
                v0 = bil_a; v1 = bil_b;
            } else {
                if (ta == ta_p + 1) {    // lower slice = previous upper
                    v0 = bil_b;
                } else {
                    const float* p = fc + ta * HWs;
                    float2 t_ = ld2(p);
                    float2 b_ = ld2(p + W_SZ);
                    v0 = t_.x * w00 + t_.y * w01 + b_.x * w10 + b_.y * w11;
                }
                const float* p = fc + (ta + 1) * HWs;
                float2 t_ = ld2(p);
                float2 b_ = ld2(p + W_SZ);
                v1 = t_.x * w00 + t_.y * w01 + b_.x * w10 + b_.y * w11;
            }
            bil_a = v0; bil_b = v1; ta_p = ta;
            s[tg] = tw0a[tg] * v0 + tw1a[tg] * v1;
        }

        // ---- pool: T in registers, W/H via shuffles; masked store ----
        float* ob = out + ((size_t)r * C_CH + (c0 + cc)) * NOUT;
        #pragma unroll
        for (int td = 0; td < 4; ++td) {
            float o = s[td] + s[td + 1];
            o += __shfl_down(o, 1);   // + (hg, wg+1)
            o += __shfl_down(o, 8);   // + (hg+1, *)
            if (active)
                __builtin_nontemporal_store(0.125f * o, &ob[td * 49 + s_hw]);
        }
    }
}

extern "C" void kernel_launch(void* const* d_in, const int* in_sizes, int n_in,
                              void* d_out, int out_size, void* d_ws, size_t ws_size,
                              hipStream_t stream) {
    const float* features = (const float*)d_in[0];
    const float* rois     = (const float*)d_in[1];
    float* out            = (float*)d_out;

    int R = in_sizes[1] / 7;   // 1024
    int nblocks = R * (C_CH / CH);
    hipLaunchKernelGGL(roialign3d_kernel, dim3(nblocks), dim3(256), 0, stream,
                       features, rois, out);
}